// Round 13
// baseline (81.896 us; speedup 1.0000x reference)
//
#include <hip/hip_runtime.h>
#include <math.h>

#define BB 8
#define TT 200
#define UU 50          // label positions; alpha lattice has U1 = 51 columns
#define VV 1024
#define U1 (UU + 1)
#define NROWS (BB * TT * U1)   // 81600 softmax rows
#define NBLK 2048              // persistent: ~8 blocks/CU, 8192 waves, ~10 rows/wave

#define LOG2E 1.44269504088896340736f
#define LN2   0.69314718055994530942f

typedef float f4v __attribute__((ext_vector_type(4)));   // nontemporal-compatible

// DPP wave_shr:1 — lane i gets lane i-1's value, lane 0 gets 0.
__device__ __forceinline__ float wave_shr1(float x) {
    int xi = __builtin_bit_cast(int, x);
    int r  = __builtin_amdgcn_update_dpp(0, xi, 0x138, 0xF, 0xF, true);
    return __builtin_bit_cast(float, r);
}

// ---------------- Kernel 1: row-wise logZ; emit only lp_blank & lp_emit ---------
// R10 body (one wave per row, 4 nt float4 loads, in-register label pick),
// wrapped in a persistent grid-stride loop: waves stay resident for ~10 rows,
// eliminating workgroup launch churn. Register footprint identical to R10
// (buffers reused each iteration; no pipeline state).
__global__ __launch_bounds__(256) void k_logp(const float* __restrict__ acts,
                                              const int* __restrict__ labels,
                                              float* __restrict__ lpb,
                                              float* __restrict__ lpe,
                                              float* __restrict__ out) {
    if (blockIdx.x == 0 && threadIdx.x == 0) out[0] = 0.0f;
    const int wave = threadIdx.x >> 6;
    const int lane = threadIdx.x & 63;
    const int stride = NBLK * 4;

    for (int row = blockIdx.x * 4 + wave; row < NROWS; row += stride) {
        int b   = row / (TT * U1);
        int rem = row - b * (TT * U1);
        int t   = rem / U1;
        int u   = rem - t * U1;
        int lab = (u < UU) ? labels[b * UU + u] : 0;

        const f4v* p = (const f4v*)(acts + (size_t)row * VV);
        f4v v0 = __builtin_nontemporal_load(p + lane);
        f4v v1 = __builtin_nontemporal_load(p + 64 + lane);
        f4v v2 = __builtin_nontemporal_load(p + 128 + lane);
        f4v v3 = __builtin_nontemporal_load(p + 192 + lane);

        const int cidx = lab >> 8, lidx = (lab >> 2) & 63, eidx = lab & 3;
        float alab = 0.0f;

        float sum = __expf(v0.x) + __expf(v0.y) + __expf(v0.z) + __expf(v0.w);
        if (cidx == 0) alab = (eidx & 2) ? ((eidx & 1) ? v0.w : v0.z) : ((eidx & 1) ? v0.y : v0.x);
        sum += __expf(v1.x) + __expf(v1.y) + __expf(v1.z) + __expf(v1.w);
        if (cidx == 1) alab = (eidx & 2) ? ((eidx & 1) ? v1.w : v1.z) : ((eidx & 1) ? v1.y : v1.x);
        sum += __expf(v2.x) + __expf(v2.y) + __expf(v2.z) + __expf(v2.w);
        if (cidx == 2) alab = (eidx & 2) ? ((eidx & 1) ? v2.w : v2.z) : ((eidx & 1) ? v2.y : v2.x);
        sum += __expf(v3.x) + __expf(v3.y) + __expf(v3.z) + __expf(v3.w);
        if (cidx == 3) alab = (eidx & 2) ? ((eidx & 1) ? v3.w : v3.z) : ((eidx & 1) ? v3.y : v3.x);

#pragma unroll
        for (int s = 1; s < 64; s <<= 1) sum += __shfl_xor(sum, s, 64);

        float logZ = __logf(sum);
        if (u < UU && lane == lidx) lpe[(b * TT + t) * UU + u] = alab - logZ;
        if (lane == 0)              lpb[row] = v0.x - logZ;
    }
}

// ---------------- Kernel 2: anti-diagonal DP + one atomicAdd per block ----------
// One block per batch. 256 threads stage lpb/lpe (base-2 scaled) into LDS,
// wave 0 walks diagonals 1..dtgt (early exit), one lane atomicAdds -loglike
// into out[0] (zeroed by k_logp earlier in the stream).
__global__ __launch_bounds__(256) void k_dp(const float* __restrict__ lpb,
                                            const float* __restrict__ lpe,
                                            const int* __restrict__ act_lens,
                                            const int* __restrict__ label_lens,
                                            float* __restrict__ out) {
    __shared__ __align__(16) float s_lpb[TT * U1];   // 40.8 KB
    __shared__ __align__(16) float s_lpe[TT * UU];   // 40.0 KB

    const int b = blockIdx.x;
    const float4* gb4 = (const float4*)(lpb + (size_t)b * TT * U1);
    const float4* ge4 = (const float4*)(lpe + (size_t)b * TT * UU);
    float4* sb4 = (float4*)s_lpb;
    float4* se4 = (float4*)s_lpe;
    for (int i = threadIdx.x; i < TT * U1 / 4; i += 256) {
        float4 v = gb4[i];
        v.x *= LOG2E; v.y *= LOG2E; v.z *= LOG2E; v.w *= LOG2E;
        sb4[i] = v;
    }
    for (int i = threadIdx.x; i < TT * UU / 4; i += 256) {
        float4 v = ge4[i];
        v.x *= LOG2E; v.y *= LOG2E; v.z *= LOG2E; v.w *= LOG2E;
        se4[i] = v;
    }
    __syncthreads();
    if (threadIdx.x >= 64) return;

    const int u  = threadIdx.x;        // lane == u; lanes 51..63 carry -inf
    const int uc = min(u, UU);
    const int tl = act_lens[b] - 1;
    const int ul = label_lens[b];
    const int dtgt = tl + ul;          // block-uniform: loop only this far
    const float NEG = -INFINITY;
    const float bsave = s_lpb[tl * U1 + ul];

    float Aprev = (u == 0) ? 0.0f : NEG;
    float saved = (dtgt == 0 && u == 0) ? bsave : NEG;

#pragma unroll 5
    for (int d = 1; d <= dtgt; ++d) {
        float Aup = wave_shr1(Aprev);
        int t  = d - u;
        int tb = min(max(t - 1, 0), TT - 1);
        int te = min(max(t, 0), TT - 1);
        float bv = s_lpb[tb * U1 + uc];
        float ev = s_lpe[te * UU + max(uc - 1, 0)];
        bool cellok = (t >= 0) & (t < TT) & (u <= UU);
        float ft = (cellok & (t >= 1)) ? Aprev + bv : NEG;
        float em = (cellok & (u >= 1)) ? Aup + ev   : NEG;
        float mm = fmaxf(ft, em);
        float dd = fminf(ft, em) - mm;
        float A  = mm + __builtin_amdgcn_logf(1.0f + __builtin_amdgcn_exp2f(dd));
        A = cellok ? A : NEG;
        saved = (d == dtgt && u == ul) ? A + bsave : saved;
        Aprev = A;
    }
    if (u == ul) atomicAdd(out, -(saved * LN2));
}

extern "C" void kernel_launch(void* const* d_in, const int* in_sizes, int n_in,
                              void* d_out, int out_size, void* d_ws, size_t ws_size,
                              hipStream_t stream) {
    const float* acts       = (const float*)d_in[0];
    const int*   labels     = (const int*)d_in[1];
    const int*   act_lens   = (const int*)d_in[2];
    const int*   label_lens = (const int*)d_in[3];

    float* ws  = (float*)d_ws;
    float* lpb = ws;                         // B*T*U1  = 81600 floats
    float* lpe = lpb + NROWS;                // B*T*U   = 80000 floats
    float* out = (float*)d_out;

    k_logp<<<NBLK, 256, 0, stream>>>(acts, labels, lpb, lpe, out);
    k_dp<<<BB, 256, 0, stream>>>(lpb, lpe, act_lens, label_lens, out);
}

// Round 14
// 75.503 us; speedup vs baseline: 1.0847x; 1.0847x over previous
//
#include <hip/hip_runtime.h>
#include <math.h>

#define BB 8
#define TT 200
#define UU 50          // label positions; alpha lattice has U1 = 51 columns
#define VV 1024
#define U1 (UU + 1)
#define NROWS (BB * TT * U1)   // 81600 softmax rows

#define LOG2E 1.44269504088896340736f
#define LN2   0.69314718055994530942f

typedef float f4v __attribute__((ext_vector_type(4)));   // nontemporal-compatible

// DPP wave_shr:1 — lane i gets lane i-1's value, lane 0 gets 0.
__device__ __forceinline__ float wave_shr1(float x) {
    int xi = __builtin_bit_cast(int, x);
    int r  = __builtin_amdgcn_update_dpp(0, xi, 0x138, 0xF, 0xF, true);
    return __builtin_bit_cast(float, r);
}

// ---------------- Kernel 1: row-wise logZ; emit only lp_blank & lp_emit ---------
// One wave per row, nontemporal acts loads (best-measured config: 75.5 µs).
// Also zeroes out[0] so k_dp can atomicAdd into it (idempotent per replay).
__global__ __launch_bounds__(256) void k_logp(const float* __restrict__ acts,
                                              const int* __restrict__ labels,
                                              float* __restrict__ lpb,
                                              float* __restrict__ lpe,
                                              float* __restrict__ out) {
    if (blockIdx.x == 0 && threadIdx.x == 0) out[0] = 0.0f;
    const int wave = threadIdx.x >> 6;
    const int lane = threadIdx.x & 63;
    const int row  = blockIdx.x * 4 + wave;          // exact: grid*4 == NROWS

    int b   = row / (TT * U1);
    int rem = row - b * (TT * U1);
    int t   = rem / U1;
    int u   = rem - t * U1;
    int lab = (u < UU) ? labels[b * UU + u] : 0;     // issued before bulk loads

    const f4v* p = (const f4v*)(acts + (size_t)row * VV);
    f4v v0 = __builtin_nontemporal_load(p + lane);
    f4v v1 = __builtin_nontemporal_load(p + 64 + lane);
    f4v v2 = __builtin_nontemporal_load(p + 128 + lane);
    f4v v3 = __builtin_nontemporal_load(p + 192 + lane);

    const int cidx = lab >> 8, lidx = (lab >> 2) & 63, eidx = lab & 3;
    float alab = 0.0f;

    float sum = __expf(v0.x) + __expf(v0.y) + __expf(v0.z) + __expf(v0.w);
    if (cidx == 0) alab = (eidx & 2) ? ((eidx & 1) ? v0.w : v0.z) : ((eidx & 1) ? v0.y : v0.x);
    sum += __expf(v1.x) + __expf(v1.y) + __expf(v1.z) + __expf(v1.w);
    if (cidx == 1) alab = (eidx & 2) ? ((eidx & 1) ? v1.w : v1.z) : ((eidx & 1) ? v1.y : v1.x);
    sum += __expf(v2.x) + __expf(v2.y) + __expf(v2.z) + __expf(v2.w);
    if (cidx == 2) alab = (eidx & 2) ? ((eidx & 1) ? v2.w : v2.z) : ((eidx & 1) ? v2.y : v2.x);
    sum += __expf(v3.x) + __expf(v3.y) + __expf(v3.z) + __expf(v3.w);
    if (cidx == 3) alab = (eidx & 2) ? ((eidx & 1) ? v3.w : v3.z) : ((eidx & 1) ? v3.y : v3.x);

#pragma unroll
    for (int s = 1; s < 64; s <<= 1) sum += __shfl_xor(sum, s, 64);

    float logZ = __logf(sum);                        // all lanes hold it
    if (u < UU && lane == lidx) lpe[(b * TT + t) * UU + u] = alab - logZ;
    if (lane == 0)              lpb[row] = v0.x - logZ;
}

// ---------------- Kernel 2: anti-diagonal DP + one atomicAdd per block ----------
// One block per batch. 256 threads stage lpb/lpe (base-2 scaled) into LDS,
// wave 0 walks the 250 diagonals, then one lane atomicAdds -loglike into
// out[0] (zeroed by k_logp earlier in the same stream).
__global__ __launch_bounds__(256) void k_dp(const float* __restrict__ lpb,
                                            const float* __restrict__ lpe,
                                            const int* __restrict__ act_lens,
                                            const int* __restrict__ label_lens,
                                            float* __restrict__ out) {
    __shared__ __align__(16) float s_lpb[TT * U1];   // 40.8 KB
    __shared__ __align__(16) float s_lpe[TT * UU];   // 40.0 KB

    const int b = blockIdx.x;
    const float4* gb4 = (const float4*)(lpb + (size_t)b * TT * U1);
    const float4* ge4 = (const float4*)(lpe + (size_t)b * TT * UU);
    float4* sb4 = (float4*)s_lpb;
    float4* se4 = (float4*)s_lpe;
    for (int i = threadIdx.x; i < TT * U1 / 4; i += 256) {
        float4 v = gb4[i];
        v.x *= LOG2E; v.y *= LOG2E; v.z *= LOG2E; v.w *= LOG2E;
        sb4[i] = v;
    }
    for (int i = threadIdx.x; i < TT * UU / 4; i += 256) {
        float4 v = ge4[i];
        v.x *= LOG2E; v.y *= LOG2E; v.z *= LOG2E; v.w *= LOG2E;
        se4[i] = v;
    }
    __syncthreads();
    if (threadIdx.x >= 64) return;

    const int u  = threadIdx.x;        // lane == u; lanes 51..63 carry -inf
    const int uc = min(u, UU);
    const int tl = act_lens[b] - 1;
    const int ul = label_lens[b];
    const int dtgt = tl + ul;
    const float NEG = -INFINITY;
    const float bsave = s_lpb[tl * U1 + ul];

    float Aprev = (u == 0) ? 0.0f : NEG;
    float saved = (dtgt == 0 && u == 0) ? bsave : NEG;

#pragma unroll 5
    for (int d = 1; d <= TT - 1 + UU; ++d) {
        float Aup = wave_shr1(Aprev);
        int t  = d - u;
        int tb = min(max(t - 1, 0), TT - 1);
        int te = min(max(t, 0), TT - 1);
        float bv = s_lpb[tb * U1 + uc];
        float ev = s_lpe[te * UU + max(uc - 1, 0)];
        bool cellok = (t >= 0) & (t < TT) & (u <= UU);
        float ft = (cellok & (t >= 1)) ? Aprev + bv : NEG;
        float em = (cellok & (u >= 1)) ? Aup + ev   : NEG;
        float mm = fmaxf(ft, em);
        float dd = fminf(ft, em) - mm;
        float A  = mm + __builtin_amdgcn_logf(1.0f + __builtin_amdgcn_exp2f(dd));
        A = cellok ? A : NEG;
        saved = (d == dtgt && u == ul) ? A + bsave : saved;
        Aprev = A;
    }
    if (u == ul) atomicAdd(out, -(saved * LN2));
}

extern "C" void kernel_launch(void* const* d_in, const int* in_sizes, int n_in,
                              void* d_out, int out_size, void* d_ws, size_t ws_size,
                              hipStream_t stream) {
    const float* acts       = (const float*)d_in[0];
    const int*   labels     = (const int*)d_in[1];
    const int*   act_lens   = (const int*)d_in[2];
    const int*   label_lens = (const int*)d_in[3];

    float* ws  = (float*)d_ws;
    float* lpb = ws;                         // B*T*U1  = 81600 floats
    float* lpe = lpb + NROWS;                // B*T*U   = 80000 floats
    float* out = (float*)d_out;

    k_logp<<<NROWS / 4, 256, 0, stream>>>(acts, labels, lpb, lpe, out);
    k_dp<<<BB, 256, 0, stream>>>(lpb, lpe, act_lens, label_lens, out);
}